// Round 2
// baseline (235.354 us; speedup 1.0000x reference)
//
#include <hip/hip_runtime.h>

#define N_TOK 65536
#define DIN   256
#define DOUT  256
#define NEXP  8
#define NPAIR 28   // C(8,2)

typedef __bf16 bf16x8 __attribute__((ext_vector_type(8)));
typedef __bf16 bf16x4 __attribute__((ext_vector_type(4)));
typedef float  f32x4  __attribute__((ext_vector_type(4)));

// global -> LDS async DMA, 16B per lane. LDS dst is wave-uniform base + lane*16
// (HW takes readfirstlane of the pointer); pass each lane's own &lds[slot*8].
__device__ __forceinline__ void cp16_g2l(const void* g, void* l) {
  auto gp = (const __attribute__((address_space(1))) unsigned int*)(unsigned long long)g;
  auto lp = (__attribute__((address_space(3))) unsigned int*)(unsigned long long)l;
  __builtin_amdgcn_global_load_lds(gp, lp, 16, 0, 0);
}

// ---------------------------------------------------------------------------
// prep: Wt[e][n][k] = bf16(We[e][k][n]) via LDS-tiled transpose (coalesced
// both directions), and zero the 28 pair counters.
// grid = 8 experts * 16 tiles of 64x64, block = 256.
// ---------------------------------------------------------------------------
__global__ __launch_bounds__(256) void prep_kernel(const float* __restrict__ We,
                                                   __bf16* __restrict__ Wt,
                                                   int* __restrict__ cnt) {
  __shared__ float T[64 * 65];
  int bid = blockIdx.x;
  if (bid == 0 && threadIdx.x < NPAIR) cnt[threadIdx.x] = 0;
  int e = bid >> 4;
  int tk = (bid >> 2) & 3, tn = bid & 3;
  int k0 = tk * 64, n0 = tn * 64;
  int tid = threadIdx.x;
  int cr = tid >> 6;     // 0..3
  int cc = tid & 63;     // coalesced lane dim
#pragma unroll
  for (int i = 0; i < 16; i++) {
    int k = i * 4 + cr;
    T[cc * 65 + k] = We[(size_t)(e * 256 + k0 + k) * 256 + n0 + cc];  // read n-contig
  }
  __syncthreads();
#pragma unroll
  for (int i = 0; i < 16; i++) {
    int n = i * 4 + cr;
    Wt[(size_t)(e * 256 + n0 + n) * 256 + k0 + cc] = (__bf16)T[n * 65 + cc];  // write k-contig
  }
}

// ---------------------------------------------------------------------------
// router: fp32 logits (np-selection-safe via fp64 recompute when the 2nd/3rd
// gap < 5e-3; 1st/2nd order is output-invariant). Also emits xb = bf16(x).
//
// Layout: 1 wave per block, 64 tokens per block, grid = 1024.
// K is processed in 8 chunks of 32 floats. Each chunk (full 64-row coverage:
// each thread stages 8 octets, rows i*8+sr for i=0..7):
//   - coalesced global float4 loads (8 lanes cover a contiguous 128B row
//     segment; 8 rows per instruction) into registers,
//   - fused bf16 convert + coalesced xb store,
//   - ds_write into an XOR-octet swizzled [64 x 32]f32 tile (16B aligned;
//     physical octet po = so ^ (row&7); per-8-lane phase all 32 banks hit
//     once -> conflict-free b128 both directions),
//   - next chunk's loads issued BEFORE the FMA phase (latency overlap),
//   - each thread reads its own token row back and accumulates 8 logits in
//     the same FP order as the row-per-thread original -> bitwise-identical
//     logits.
// Wr is indexed wave-uniformly -> scalar loads (8KB, sL1-hot).
// Per-pair bucket append with block-aggregated atomics.
// ---------------------------------------------------------------------------
__global__ __launch_bounds__(64) void router_kernel(const float* __restrict__ x,
                                                    const float* __restrict__ Wr,
                                                    __bf16* __restrict__ xb,
                                                    int* __restrict__ cnt,
                                                    unsigned short* __restrict__ pidx,
                                                    float* __restrict__ pw) {
  __shared__ float X[64 * 32];   // swizzled octets, no padding needed
  __shared__ int lcnt[NPAIR];
  __shared__ int gbase[NPAIR];
  int tid = threadIdx.x;
  if (tid < NPAIR) lcnt[tid] = 0;

  int tokBase = blockIdx.x * 64;
  int token = tokBase + tid;

  const int sr = tid >> 3;          // 0..7: row-within-8-group this thread stages
  const int so = tid & 7;           // 0..7: logical octet (16B) this thread stages
  const int po = so ^ sr;           // physical octet after XOR swizzle (r&7 == sr for all i)
  const int ro = tid & 7;           // row&7 for this thread's OWN row (read side)

  float acc[NEXP];
#pragma unroll
  for (int e = 0; e < NEXP; e++) acc[e] = 0.f;

  float4 v[8];
#pragma unroll
  for (int i = 0; i < 8; i++)
    v[i] = *(const float4*)&x[(size_t)(tokBase + i * 8 + sr) * DIN + so * 4];

  for (int kc = 0; kc < 8; kc++) {
    // stage current chunk: LDS (swizzled) + xb (bf16, coalesced). 8 octets per
    // thread -> full 64 rows x 32 floats covered.
#pragma unroll
    for (int i = 0; i < 8; i++) {
      int r = i * 8 + sr;
      *(float4*)&X[((r * 8 + po)) * 4] = v[i];
      bf16x4 bv;
      bv[0] = (__bf16)v[i].x; bv[1] = (__bf16)v[i].y;
      bv[2] = (__bf16)v[i].z; bv[3] = (__bf16)v[i].w;
      *(bf16x4*)&xb[(size_t)(tokBase + r) * DIN + kc * 32 + so * 4] = bv;
    }
    __syncthreads();
    // issue next chunk's loads before compute (overlap HBM latency with FMAs)
    if (kc < 7) {
#pragma unroll
      for (int i = 0; i < 8; i++)
        v[i] = *(const float4*)&x[(size_t)(tokBase + i * 8 + sr) * DIN + (kc + 1) * 32 + so * 4];
    }
    // compute: this thread's own token row, same FP order as original
#pragma unroll
    for (int i4 = 0; i4 < 8; i4++) {
      float4 xv = *(const float4*)&X[((tid * 8 + (i4 ^ ro))) * 4];
      const float* w0 = &Wr[(kc * 32 + i4 * 4) * NEXP];   // wave-uniform -> s_load
#pragma unroll
      for (int e = 0; e < NEXP; e++)
        acc[e] += xv.x * w0[e] + xv.y * w0[NEXP + e] + xv.z * w0[2 * NEXP + e] + xv.w * w0[3 * NEXP + e];
    }
    __syncthreads();
  }

  int best = 0;
#pragma unroll
  for (int e = 1; e < NEXP; e++) if (acc[e] > acc[best]) best = e;
  int sec = (best == 0) ? 1 : 0;
#pragma unroll
  for (int e = 0; e < NEXP; e++)
    if (e != best && e != sec && acc[e] > acc[sec]) sec = e;
  float l3 = -1e30f;
#pragma unroll
  for (int e = 0; e < NEXP; e++)
    if (e != best && e != sec) l3 = fmaxf(l3, acc[e]);

  float diff = acc[sec] - acc[best];       // <= 0
  bool need = (acc[sec] - l3) < 5e-3f;     // 2nd-vs-3rd near-tie -> fp64
  if (__any(need)) {
    if (need) {
      const float4* xr = (const float4*)(x + (size_t)token * DIN);
      double d[NEXP];
#pragma unroll
      for (int e = 0; e < NEXP; e++) d[e] = 0.0;
      for (int i4 = 0; i4 < DIN / 4; i4++) {
        float4 vv = xr[i4];
        const float* w0 = &Wr[(i4 * 4) * NEXP];
#pragma unroll
        for (int e = 0; e < NEXP; e++)
          d[e] += (double)vv.x * w0[e] + (double)vv.y * w0[NEXP + e] +
                  (double)vv.z * w0[2 * NEXP + e] + (double)vv.w * w0[3 * NEXP + e];
      }
      best = 0;
#pragma unroll
      for (int e = 1; e < NEXP; e++) if (d[e] > d[best]) best = e;
      sec = (best == 0) ? 1 : 0;
#pragma unroll
      for (int e = 0; e < NEXP; e++)
        if (e != best && e != sec && d[e] > d[sec]) sec = e;
      diff = (float)(d[sec] - d[best]);
    }
  }

  float wb = 1.f / (1.f + expf(diff));     // weight of `best` after renorm
  int a, b2; float wa;
  if (best < sec) { a = best; b2 = sec; wa = wb; }
  else            { a = sec;  b2 = best; wa = 1.f - wb; }
  int p = a * (15 - a) / 2 + (b2 - a - 1);

  int lpos = atomicAdd(&lcnt[p], 1);
  __syncthreads();
  if (tid < NPAIR) gbase[tid] = atomicAdd(&cnt[tid], lcnt[tid]);
  __syncthreads();
  int pos = gbase[p] + lpos;
  pidx[p * N_TOK + pos] = (unsigned short)token;
  pw[p * N_TOK + pos] = wa;
}

// ---------------------------------------------------------------------------
// grouped GEMM, dual-accumulator form: out = wa*(x@Wa + ba) + wb*(x@Wb + bb).
// Block tile: 128 tokens x 64 cols (nh in 0..3), K=256 in 4 chunks of 64.
// A (xb rows) staged via async global_load_lds with XOR-octet swizzle
// (conflict-free ds_read_b128, no padding needed). B read direct from global
// (Wt is 1MB, L1/L2-hot). 4 waves: 2x2 over (64 tok x 32 cols), dual 4x2 acc.
// Output written exactly once, no atomics.
// ---------------------------------------------------------------------------
__global__ __launch_bounds__(256) void moe_gemm_kernel(const __bf16* __restrict__ xb,
                                                       const __bf16* __restrict__ Wt,
                                                       const float* __restrict__ be,
                                                       const int* __restrict__ cnt,
                                                       const unsigned short* __restrict__ pidx,
                                                       const float* __restrict__ pw,
                                                       float* __restrict__ out) {
  // As slot layout: (row r, octet j') at byte offset (r*8 + j')*16 where the
  // octet stored in slot j' is s8 = j' ^ (r&7)  (XOR swizzle -> all 32 banks).
  __shared__ __bf16 As[128 * 64];
  __shared__ unsigned short tokL[128];
  __shared__ float wL[128];
  __shared__ int meta[4];

  int tid = threadIdx.x;
  int tile = blockIdx.x >> 2;
  int nh = blockIdx.x & 3;

  if (tid == 0) {
    int s = 0, pp = -1, lt = 0, c = 0;
    for (int q = 0; q < NPAIR; q++) {
      int cq = cnt[q];
      int tq = (cq + 127) >> 7;
      if (tile < s + tq) { pp = q; lt = tile - s; c = cq; break; }
      s += tq;
    }
    meta[0] = pp; meta[1] = lt; meta[2] = c;
  }
  __syncthreads();
  int p = meta[0];
  if (p < 0) return;
  int lt = meta[1], cnt_p = meta[2];

  int a = 0, rem = p;
  while (rem >= 7 - a) { rem -= 7 - a; a++; }
  int b2 = a + 1 + rem;
  int r0 = lt * 128;

  if (tid < 128) {
    int gr = r0 + tid;
    tokL[tid] = (gr < cnt_p) ? pidx[p * N_TOK + gr] : (unsigned short)0;
    wL[tid]   = (gr < cnt_p) ? pw[p * N_TOK + gr] : 0.f;
  }
  __syncthreads();

  const int lane = tid & 63, wid = tid >> 6;
  const int wm = wid & 1, wn = wid >> 1;
  const int c16 = lane & 15, quad = lane >> 4;

  // staging geometry: thread handles slots tid + 256*i -> row r = tid>>3 + 32*i,
  // slot-octet j' = tid&7, global octet s8 = j' ^ (r&7) (r&7 same for all i).
  const int r_base = tid >> 3;
  const int s8 = (tid & 7) ^ (r_base & 7);
  size_t grow[4];
#pragma unroll
  for (int i = 0; i < 4; i++)
    grow[i] = (size_t)tokL[r_base + 32 * i] * DIN + s8 * 8;

  const __bf16* WtA = Wt + ((size_t)a * DOUT + nh * 64) * DIN;
  const __bf16* WtB = Wt + ((size_t)b2 * DOUT + nh * 64) * DIN;

  f32x4 accA[4][2], accB[4][2];
#pragma unroll
  for (int mi = 0; mi < 4; mi++)
#pragma unroll
    for (int ni = 0; ni < 2; ni++)
#pragma unroll
      for (int r = 0; r < 4; r++) { accA[mi][ni][r] = 0.f; accB[mi][ni][r] = 0.f; }

  for (int kc = 0; kc < 4; kc++) {
#pragma unroll
    for (int i = 0; i < 4; i++) {
      int slot = tid + 256 * i;
      cp16_g2l(xb + grow[i] + kc * 64, &As[slot * 8]);
    }
    __builtin_amdgcn_s_waitcnt(0x0F70);  // vmcnt(0): DMA landed in LDS
    __syncthreads();
#pragma unroll
    for (int ks = 0; ks < 2; ks++) {
      bf16x8 af[4], ba[2], bb[2];
#pragma unroll
      for (int mi = 0; mi < 4; mi++) {
        int row = wm * 64 + mi * 16 + c16;
        int oct = ks * 4 + quad;
        af[mi] = *(const bf16x8*)&As[(row * 8 + (oct ^ (row & 7))) * 8];
      }
#pragma unroll
      for (int ni = 0; ni < 2; ni++) {
        int col = wn * 32 + ni * 16 + c16;
        int koff = kc * 64 + ks * 32 + quad * 8;
        ba[ni] = *(const bf16x8*)&WtA[(size_t)col * DIN + koff];
        bb[ni] = *(const bf16x8*)&WtB[(size_t)col * DIN + koff];
      }
#pragma unroll
      for (int mi = 0; mi < 4; mi++)
#pragma unroll
        for (int ni = 0; ni < 2; ni++) {
          accA[mi][ni] = __builtin_amdgcn_mfma_f32_16x16x32_bf16(af[mi], ba[ni], accA[mi][ni], 0, 0, 0);
          accB[mi][ni] = __builtin_amdgcn_mfma_f32_16x16x32_bf16(af[mi], bb[ni], accB[mi][ni], 0, 0, 0);
        }
    }
    __syncthreads();
  }

  // epilogue: weights + biases in fp32, store exactly once
#pragma unroll
  for (int ni = 0; ni < 2; ni++) {
    int gcol = nh * 64 + wn * 32 + ni * 16 + c16;
    float bea = be[a * DOUT + gcol];
    float beb = be[b2 * DOUT + gcol];
#pragma unroll
    for (int mi = 0; mi < 4; mi++) {
#pragma unroll
      for (int r = 0; r < 4; r++) {
        int row = wm * 64 + mi * 16 + quad * 4 + r;
        if (r0 + row < cnt_p) {
          float w = wL[row];
          out[(size_t)tokL[row] * DOUT + gcol] =
              w * (accA[mi][ni][r] + bea) + (1.f - w) * (accB[mi][ni][r] + beb);
        }
      }
    }
  }
}

// ---------------------------------------------------------------------------
extern "C" void kernel_launch(void* const* d_in, const int* in_sizes, int n_in,
                              void* d_out, int out_size, void* d_ws, size_t ws_size,
                              hipStream_t stream) {
  const float* x  = (const float*)d_in[0];
  const float* Wr = (const float*)d_in[1];
  const float* We = (const float*)d_in[2];
  const float* be = (const float*)d_in[3];
  float* out = (float*)d_out;

  // ws layout (~44.1 MB):
  //   [0, 1MB)        : Wt  bf16 [8][256][256]  ([e][n][k])
  //   [1MB, 33MB)     : xb  bf16 [65536][256]
  //   [33MB, +512B)   : cnt[28]
  //   [+, +3.5MB)     : pidx ushort [28][65536]
  //   [+, +7MB)       : pw   float  [28][65536]
  char* w = (char*)d_ws;
  __bf16* Wt = (__bf16*)w;
  __bf16* xb = (__bf16*)(w + (1u << 20));
  int* cnt = (int*)(w + (33u << 20));
  unsigned short* pidx = (unsigned short*)(w + (33u << 20) + 512);
  float* pw = (float*)(w + (33u << 20) + 512 + (size_t)NPAIR * N_TOK * 2);

  prep_kernel<<<128, 256, 0, stream>>>(We, Wt, cnt);
  router_kernel<<<N_TOK / 64, 64, 0, stream>>>(x, Wr, xb, cnt, pidx, pw);
  // max tiles = sum_p ceil(cnt_p/128) <= 65536/128 + 28 = 540; x4 column strips
  moe_gemm_kernel<<<540 * 4, 256, 0, stream>>>(xb, Wt, be, cnt, pidx, pw, out);
}

// Round 5
// 212.685 us; speedup vs baseline: 1.1066x; 1.1066x over previous
//
#include <hip/hip_runtime.h>

#define N_TOK 65536
#define DIN   256
#define DOUT  256
#define NEXP  8
#define NPAIR 28   // C(8,2)

typedef __bf16 bf16x8 __attribute__((ext_vector_type(8)));
typedef __bf16 bf16x4 __attribute__((ext_vector_type(4)));
typedef float  f32x4  __attribute__((ext_vector_type(4)));

// global -> LDS async DMA, 16B per lane. LDS dst is wave-uniform base + lane*16
// (HW takes readfirstlane of the pointer); pass each lane's own &lds[slot*8].
__device__ __forceinline__ void cp16_g2l(const void* g, void* l) {
  auto gp = (const __attribute__((address_space(1))) unsigned int*)(unsigned long long)g;
  auto lp = (__attribute__((address_space(3))) unsigned int*)(unsigned long long)l;
  __builtin_amdgcn_global_load_lds(gp, lp, 16, 0, 0);
}

// ---------------------------------------------------------------------------
// prep: Wt[e][n][k] = bf16(We[e][k][n]) via LDS-tiled transpose (coalesced
// both directions), and zero the 28 pair counters.
// grid = 8 experts * 16 tiles of 64x64, block = 256.
// ---------------------------------------------------------------------------
__global__ __launch_bounds__(256) void prep_kernel(const float* __restrict__ We,
                                                   __bf16* __restrict__ Wt,
                                                   int* __restrict__ cnt) {
  __shared__ float T[64 * 65];
  int bid = blockIdx.x;
  if (bid == 0 && threadIdx.x < NPAIR) cnt[threadIdx.x] = 0;
  int e = bid >> 4;
  int tk = (bid >> 2) & 3, tn = bid & 3;
  int k0 = tk * 64, n0 = tn * 64;
  int tid = threadIdx.x;
  int cr = tid >> 6;     // 0..3
  int cc = tid & 63;     // coalesced lane dim
#pragma unroll
  for (int i = 0; i < 16; i++) {
    int k = i * 4 + cr;
    T[cc * 65 + k] = We[(size_t)(e * 256 + k0 + k) * 256 + n0 + cc];  // read n-contig
  }
  __syncthreads();
#pragma unroll
  for (int i = 0; i < 16; i++) {
    int n = i * 4 + cr;
    Wt[(size_t)(e * 256 + n0 + n) * 256 + k0 + cc] = (__bf16)T[n * 65 + cc];  // write k-contig
  }
}

// ---------------------------------------------------------------------------
// router v3: split-K across waves for 4x wave parallelism (16 waves/CU).
//
// Block = 256 threads (4 waves), 64 tokens/block, grid = 1024.
// K in 4 chunks of 64 floats. Per chunk:
//   - stage: flat f4 index f = tid + 256*i -> row f>>4, octet f&15; per
//     instruction the wave covers 4 rows x 16 contiguous octets = 4x256B
//     segments (coalesced). Fused bf16 convert + coalesced xb store.
//     LDS tile X[64 rows][16 octets], XOR swizzle po = o16 ^ (row&7):
//     bank group (o16&7)^(row&7) -> all 8 groups x 8 lanes per instr,
//     conflict-free b128 writes AND reads (row stride 256B == 0 mod banks,
//     so the row term cancels; the XOR re-spreads it).
//   - wave w computes k-slice [c*64 + w*16, +16) for ALL 64 tokens (one
//     token per lane) -> Wr addresses are wave-uniform -> s_load (sK$-hot).
//   - next chunk's global loads issued before compute (latency overlap).
// Partials reduced across waves via padded LDS P[64][36] in fixed
// w-ascending order. Selection/fp64-fallback/bucket append in wave 0 only
// (fallback recompute keeps the original canonical fp32/fp64 order).
// ---------------------------------------------------------------------------
__global__ __launch_bounds__(256) void router_kernel(const float* __restrict__ x,
                                                     const float* __restrict__ Wr,
                                                     __bf16* __restrict__ xb,
                                                     int* __restrict__ cnt,
                                                     unsigned short* __restrict__ pidx,
                                                     float* __restrict__ pw) {
  __shared__ float X[64 * 64];    // 16KB chunk tile (64 rows x 64 floats), swizzled
  __shared__ float P[64 * 36];    // 9KB partial logits [token][wave*8 + e], pad to 36
  __shared__ int lcnt[NPAIR];
  __shared__ int gbase[NPAIR];
  int tid = threadIdx.x;
  if (tid < NPAIR) lcnt[tid] = 0;

  const int w = __builtin_amdgcn_readfirstlane(tid >> 6);  // wave id 0..3 (SGPR)
  const int t = tid & 63;                                  // lane = token-in-block
  int tokBase = blockIdx.x * 64;

  // staging geometry: thread stages rows srow+16i (i=0..3), octet so16.
  const int srow = tid >> 4;           // 0..15
  const int so16 = tid & 15;           // 0..15
  const int spo  = so16 ^ (srow & 7);  // physical octet ((srow+16i)&7 == srow&7)

  float acc[NEXP];
#pragma unroll
  for (int e = 0; e < NEXP; e++) acc[e] = 0.f;

  float4 v[4];
#pragma unroll
  for (int i = 0; i < 4; i++)
    v[i] = *(const float4*)&x[(size_t)(tokBase + srow + 16 * i) * DIN + so16 * 4];

  for (int c = 0; c < 4; c++) {
    // stage current chunk: LDS (swizzled) + xb (bf16, coalesced)
#pragma unroll
    for (int i = 0; i < 4; i++) {
      int r = srow + 16 * i;
      *(float4*)&X[r * 64 + spo * 4] = v[i];
      bf16x4 bv;
      bv[0] = (__bf16)v[i].x; bv[1] = (__bf16)v[i].y;
      bv[2] = (__bf16)v[i].z; bv[3] = (__bf16)v[i].w;
      *(bf16x4*)&xb[(size_t)(tokBase + r) * DIN + c * 64 + so16 * 4] = bv;
    }
    __syncthreads();
    // prefetch next chunk before compute (overlap HBM latency with FMAs)
    if (c < 3) {
#pragma unroll
      for (int i = 0; i < 4; i++)
        v[i] = *(const float4*)&x[(size_t)(tokBase + srow + 16 * i) * DIN + (c + 1) * 64 + so16 * 4];
    }
    // compute: wave w's 16-float k-slice of token t (ascending k within slice)
#pragma unroll
    for (int i4 = 0; i4 < 4; i4++) {
      int po = (w * 4 + i4) ^ (t & 7);
      float4 xv = *(const float4*)&X[t * 64 + po * 4];
      const float* w0 = &Wr[(c * 64 + w * 16 + i4 * 4) * NEXP];  // wave-uniform -> s_load
#pragma unroll
      for (int e = 0; e < NEXP; e++)
        acc[e] += xv.x * w0[e] + xv.y * w0[NEXP + e] + xv.z * w0[2 * NEXP + e] + xv.w * w0[3 * NEXP + e];
    }
    __syncthreads();
  }

  // write per-wave partials (conflict-free b128: bank group (t + w*2 + p) & 7)
  f32x4 lo, hi;
#pragma unroll
  for (int e = 0; e < 4; e++) { lo[e] = acc[e]; hi[e] = acc[4 + e]; }
  *(f32x4*)&P[t * 36 + w * 8]     = lo;
  *(f32x4*)&P[t * 36 + w * 8 + 4] = hi;
  __syncthreads();
  if (tid >= 64) return;   // no further barriers below

  int token = tokBase + tid;

  // reduce across waves in fixed ascending-w order (deterministic fp32)
  f32x4 pa0 = *(const f32x4*)&P[tid * 36 + 0];
  f32x4 pa1 = *(const f32x4*)&P[tid * 36 + 8];
  f32x4 pa2 = *(const f32x4*)&P[tid * 36 + 16];
  f32x4 pa3 = *(const f32x4*)&P[tid * 36 + 24];
  f32x4 pb0 = *(const f32x4*)&P[tid * 36 + 4];
  f32x4 pb1 = *(const f32x4*)&P[tid * 36 + 12];
  f32x4 pb2 = *(const f32x4*)&P[tid * 36 + 20];
  f32x4 pb3 = *(const f32x4*)&P[tid * 36 + 28];
  f32x4 sA = ((pa0 + pa1) + pa2) + pa3;
  f32x4 sB = ((pb0 + pb1) + pb2) + pb3;
  float lg[NEXP];
#pragma unroll
  for (int e = 0; e < 4; e++) { lg[e] = sA[e]; lg[4 + e] = sB[e]; }

  int best = 0;
#pragma unroll
  for (int e = 1; e < NEXP; e++) if (lg[e] > lg[best]) best = e;
  int sec = (best == 0) ? 1 : 0;
#pragma unroll
  for (int e = 0; e < NEXP; e++)
    if (e != best && e != sec && lg[e] > lg[sec]) sec = e;
  float l3 = -1e30f;
#pragma unroll
  for (int e = 0; e < NEXP; e++)
    if (e != best && e != sec) l3 = fmaxf(l3, lg[e]);

  float diff = lg[sec] - lg[best];         // <= 0
  bool need = (lg[sec] - l3) < 5e-3f;      // 2nd-vs-3rd near-tie -> fp64
  if (__any(need)) {
    if (need) {
      const float4* xr = (const float4*)(x + (size_t)token * DIN);
      double d[NEXP];
#pragma unroll
      for (int e = 0; e < NEXP; e++) d[e] = 0.0;
      for (int i4 = 0; i4 < DIN / 4; i4++) {
        float4 vv = xr[i4];
        const float* w0 = &Wr[(i4 * 4) * NEXP];
#pragma unroll
        for (int e = 0; e < NEXP; e++)
          d[e] += (double)vv.x * w0[e] + (double)vv.y * w0[NEXP + e] +
                  (double)vv.z * w0[2 * NEXP + e] + (double)vv.w * w0[3 * NEXP + e];
      }
      best = 0;
#pragma unroll
      for (int e = 1; e < NEXP; e++) if (d[e] > d[best]) best = e;
      sec = (best == 0) ? 1 : 0;
#pragma unroll
      for (int e = 0; e < NEXP; e++)
        if (e != best && e != sec && d[e] > d[sec]) sec = e;
      diff = (float)(d[sec] - d[best]);
    }
  }

  float wb = 1.f / (1.f + expf(diff));     // weight of `best` after renorm
  int a, b2; float wa;
  if (best < sec) { a = best; b2 = sec; wa = wb; }
  else            { a = sec;  b2 = best; wa = 1.f - wb; }
  int p = a * (15 - a) / 2 + (b2 - a - 1);

  // single-wave bucket append: per-wave DS ops are in-order, so the ds_read
  // of lcnt below observes all lanes' atomics from the previous instruction.
  int lpos = atomicAdd(&lcnt[p], 1);
  if (tid < NPAIR) gbase[tid] = atomicAdd(&cnt[tid], lcnt[tid]);
  int pos = gbase[p] + lpos;
  pidx[p * N_TOK + pos] = (unsigned short)token;
  pw[p * N_TOK + pos] = wa;
}

// ---------------------------------------------------------------------------
// grouped GEMM, dual-accumulator form: out = wa*(x@Wa + ba) + wb*(x@Wb + bb).
// Block tile: 128 tokens x 64 cols (nh in 0..3), K=256 in 4 chunks of 64.
// A (xb rows) staged via async global_load_lds with XOR-octet swizzle
// (conflict-free ds_read_b128, no padding needed). B read direct from global
// (Wt is 1MB, L1/L2-hot). 4 waves: 2x2 over (64 tok x 32 cols), dual 4x2 acc.
// Output written exactly once, no atomics.
// ---------------------------------------------------------------------------
__global__ __launch_bounds__(256) void moe_gemm_kernel(const __bf16* __restrict__ xb,
                                                       const __bf16* __restrict__ Wt,
                                                       const float* __restrict__ be,
                                                       const int* __restrict__ cnt,
                                                       const unsigned short* __restrict__ pidx,
                                                       const float* __restrict__ pw,
                                                       float* __restrict__ out) {
  // As slot layout: (row r, octet j') at byte offset (r*8 + j')*16 where the
  // octet stored in slot j' is s8 = j' ^ (r&7)  (XOR swizzle -> all 32 banks).
  __shared__ __bf16 As[128 * 64];
  __shared__ unsigned short tokL[128];
  __shared__ float wL[128];
  __shared__ int meta[4];

  int tid = threadIdx.x;
  int tile = blockIdx.x >> 2;
  int nh = blockIdx.x & 3;

  if (tid == 0) {
    int s = 0, pp = -1, lt = 0, c = 0;
    for (int q = 0; q < NPAIR; q++) {
      int cq = cnt[q];
      int tq = (cq + 127) >> 7;
      if (tile < s + tq) { pp = q; lt = tile - s; c = cq; break; }
      s += tq;
    }
    meta[0] = pp; meta[1] = lt; meta[2] = c;
  }
  __syncthreads();
  int p = meta[0];
  if (p < 0) return;
  int lt = meta[1], cnt_p = meta[2];

  int a = 0, rem = p;
  while (rem >= 7 - a) { rem -= 7 - a; a++; }
  int b2 = a + 1 + rem;
  int r0 = lt * 128;

  if (tid < 128) {
    int gr = r0 + tid;
    tokL[tid] = (gr < cnt_p) ? pidx[p * N_TOK + gr] : (unsigned short)0;
    wL[tid]   = (gr < cnt_p) ? pw[p * N_TOK + gr] : 0.f;
  }
  __syncthreads();

  const int lane = tid & 63, wid = tid >> 6;
  const int wm = wid & 1, wn = wid >> 1;
  const int c16 = lane & 15, quad = lane >> 4;

  // staging geometry: thread handles slots tid + 256*i -> row r = tid>>3 + 32*i,
  // slot-octet j' = tid&7, global octet s8 = j' ^ (r&7) (r&7 same for all i).
  const int r_base = tid >> 3;
  const int s8 = (tid & 7) ^ (r_base & 7);
  size_t grow[4];
#pragma unroll
  for (int i = 0; i < 4; i++)
    grow[i] = (size_t)tokL[r_base + 32 * i] * DIN + s8 * 8;

  const __bf16* WtA = Wt + ((size_t)a * DOUT + nh * 64) * DIN;
  const __bf16* WtB = Wt + ((size_t)b2 * DOUT + nh * 64) * DIN;

  f32x4 accA[4][2], accB[4][2];
#pragma unroll
  for (int mi = 0; mi < 4; mi++)
#pragma unroll
    for (int ni = 0; ni < 2; ni++)
#pragma unroll
      for (int r = 0; r < 4; r++) { accA[mi][ni][r] = 0.f; accB[mi][ni][r] = 0.f; }

  for (int kc = 0; kc < 4; kc++) {
#pragma unroll
    for (int i = 0; i < 4; i++) {
      int slot = tid + 256 * i;
      cp16_g2l(xb + grow[i] + kc * 64, &As[slot * 8]);
    }
    __builtin_amdgcn_s_waitcnt(0x0F70);  // vmcnt(0): DMA landed in LDS
    __syncthreads();
#pragma unroll
    for (int ks = 0; ks < 2; ks++) {
      bf16x8 af[4], ba[2], bb[2];
#pragma unroll
      for (int mi = 0; mi < 4; mi++) {
        int row = wm * 64 + mi * 16 + c16;
        int oct = ks * 4 + quad;
        af[mi] = *(const bf16x8*)&As[(row * 8 + (oct ^ (row & 7))) * 8];
      }
#pragma unroll
      for (int ni = 0; ni < 2; ni++) {
        int col = wn * 32 + ni * 16 + c16;
        int koff = kc * 64 + ks * 32 + quad * 8;
        ba[ni] = *(const bf16x8*)&WtA[(size_t)col * DIN + koff];
        bb[ni] = *(const bf16x8*)&WtB[(size_t)col * DIN + koff];
      }
#pragma unroll
      for (int mi = 0; mi < 4; mi++)
#pragma unroll
        for (int ni = 0; ni < 2; ni++) {
          accA[mi][ni] = __builtin_amdgcn_mfma_f32_16x16x32_bf16(af[mi], ba[ni], accA[mi][ni], 0, 0, 0);
          accB[mi][ni] = __builtin_amdgcn_mfma_f32_16x16x32_bf16(af[mi], bb[ni], accB[mi][ni], 0, 0, 0);
        }
    }
    __syncthreads();
  }

  // epilogue: weights + biases in fp32, store exactly once
#pragma unroll
  for (int ni = 0; ni < 2; ni++) {
    int gcol = nh * 64 + wn * 32 + ni * 16 + c16;
    float bea = be[a * DOUT + gcol];
    float beb = be[b2 * DOUT + gcol];
#pragma unroll
    for (int mi = 0; mi < 4; mi++) {
#pragma unroll
      for (int r = 0; r < 4; r++) {
        int row = wm * 64 + mi * 16 + quad * 4 + r;
        if (r0 + row < cnt_p) {
          float w = wL[row];
          out[(size_t)tokL[row] * DOUT + gcol] =
              w * (accA[mi][ni][r] + bea) + (1.f - w) * (accB[mi][ni][r] + beb);
        }
      }
    }
  }
}

// ---------------------------------------------------------------------------
extern "C" void kernel_launch(void* const* d_in, const int* in_sizes, int n_in,
                              void* d_out, int out_size, void* d_ws, size_t ws_size,
                              hipStream_t stream) {
  const float* x  = (const float*)d_in[0];
  const float* Wr = (const float*)d_in[1];
  const float* We = (const float*)d_in[2];
  const float* be = (const float*)d_in[3];
  float* out = (float*)d_out;

  // ws layout (~44.1 MB):
  //   [0, 1MB)        : Wt  bf16 [8][256][256]  ([e][n][k])
  //   [1MB, 33MB)     : xb  bf16 [65536][256]
  //   [33MB, +512B)   : cnt[28]
  //   [+, +3.5MB)     : pidx ushort [28][65536]
  //   [+, +7MB)       : pw   float  [28][65536]
  char* w = (char*)d_ws;
  __bf16* Wt = (__bf16*)w;
  __bf16* xb = (__bf16*)(w + (1u << 20));
  int* cnt = (int*)(w + (33u << 20));
  unsigned short* pidx = (unsigned short*)(w + (33u << 20) + 512);
  float* pw = (float*)(w + (33u << 20) + 512 + (size_t)NPAIR * N_TOK * 2);

  prep_kernel<<<128, 256, 0, stream>>>(We, Wt, cnt);
  router_kernel<<<N_TOK / 64, 256, 0, stream>>>(x, Wr, xb, cnt, pidx, pw);
  // max tiles = sum_p ceil(cnt_p/128) <= 65536/128 + 28 = 540; x4 column strips
  moe_gemm_kernel<<<540 * 4, 256, 0, stream>>>(xb, Wt, be, cnt, pidx, pw, out);
}